// Round 1
// 1642.517 us; speedup vs baseline: 1.1619x; 1.1619x over previous
//
#include <hip/hip_runtime.h>

// Problem constants (from reference setup_inputs)
#define SZ0 1363968
#define SZ1 123904
#define SZ2 11264
#define SZ3 1024
#define NE0 1239040
#define NE1 112640
#define NE2 10240
#define DIN 128
#define DH  256
#define DOUT 64

// ---------------------------------------------------------------------------
// 1) Degree histogram: bk[dst]++  (int atomics, E total, ~10 per counter)
// ---------------------------------------------------------------------------
__global__ __launch_bounds__(256) void edge_hist(
    const int* __restrict__ dst, int* __restrict__ bk, int E)
{
    int e = blockIdx.x * 256 + threadIdx.x;
    if (e < E) atomicAdd(&bk[dst[e]], 1);
}

// ---------------------------------------------------------------------------
// 2) In-place exclusive scan over n counters (single 1024-thread block).
//    n is a multiple of 1024 for all layers -> every chunk is full.
// ---------------------------------------------------------------------------
__global__ __launch_bounds__(1024) void scan_inplace(int* __restrict__ a, int n)
{
    __shared__ int sums[1024];
    const int t = threadIdx.x;
    const int C = (n + 1023) >> 10;
    const int lo = t * C;
    const int hi = min(lo + C, n);
    int s = 0;
    for (int i = lo; i < hi; i++) s += a[i];
    sums[t] = s;
    __syncthreads();
    for (int off = 1; off < 1024; off <<= 1) {
        int v = (t >= off) ? sums[t - off] : 0;
        __syncthreads();
        sums[t] += v;
        __syncthreads();
    }
    int pre = (t == 0) ? 0 : sums[t - 1];
    for (int i = lo; i < hi; i++) { int v = a[i]; a[i] = pre; pre += v; }
}

// ---------------------------------------------------------------------------
// 3) Ticket-scatter src into dst-sorted buckets. After this kernel,
//    bk[d] == end offset of bucket d (start = bk[d-1], or 0 for d==0).
// ---------------------------------------------------------------------------
__global__ __launch_bounds__(256) void edge_bucket(
    const int* __restrict__ src, const int* __restrict__ dst,
    int* __restrict__ bk, int* __restrict__ perm, int E)
{
    int e = blockIdx.x * 256 + threadIdx.x;
    if (e < E) {
        int pos = atomicAdd(&bk[dst[e]], 1);
        perm[pos] = src[e];
    }
}

// ---------------------------------------------------------------------------
// 4) Segmented gather-mean: one wave (64 lanes) per dst row.
//    D=128 -> float2/lane, D=256 -> float4/lane. 512B/1KB contiguous per row.
//    Unroll x2 over edges: two independent X-row loads in flight per wave
//    (the serial perm->row dependent chain was limiting MLP at ~75% of BW).
//    Writes EVERY row (0 for empty buckets) -> no pre-zeroing of out needed.
// ---------------------------------------------------------------------------
template <int D>
__global__ __launch_bounds__(256) void gather_mean(
    const float* __restrict__ X, const int* __restrict__ perm,
    const int* __restrict__ ends, float* __restrict__ out)
{
    constexpr int VEC = D / 64;
    const int wave = (blockIdx.x * 256 + threadIdx.x) >> 6;
    const int lane = threadIdx.x & 63;
    const int start = (wave == 0) ? 0 : ends[wave - 1];
    const int end = ends[wave];

    float acc0[VEC], acc1[VEC];
#pragma unroll
    for (int i = 0; i < VEC; i++) { acc0[i] = 0.0f; acc1[i] = 0.0f; }

    int e = start;
    for (; e + 2 <= end; e += 2) {
        int s0 = perm[e];
        int s1 = perm[e + 1];
        const float* p0 = X + (size_t)s0 * D + lane * VEC;
        const float* p1 = X + (size_t)s1 * D + lane * VEC;
        if (VEC == 2) {
            float2 v0 = *reinterpret_cast<const float2*>(p0);
            float2 v1 = *reinterpret_cast<const float2*>(p1);
            acc0[0] += v0.x; acc0[1] += v0.y;
            acc1[0] += v1.x; acc1[1] += v1.y;
        } else {
            float4 v0 = *reinterpret_cast<const float4*>(p0);
            float4 v1 = *reinterpret_cast<const float4*>(p1);
            acc0[0] += v0.x; acc0[1] += v0.y; acc0[2] += v0.z; acc0[3] += v0.w;
            acc1[0] += v1.x; acc1[1] += v1.y; acc1[2] += v1.z; acc1[3] += v1.w;
        }
    }
    if (e < end) {
        int s0 = perm[e];
        const float* p0 = X + (size_t)s0 * D + lane * VEC;
        if (VEC == 2) {
            float2 v0 = *reinterpret_cast<const float2*>(p0);
            acc0[0] += v0.x; acc0[1] += v0.y;
        } else {
            float4 v0 = *reinterpret_cast<const float4*>(p0);
            acc0[0] += v0.x; acc0[1] += v0.y; acc0[2] += v0.z; acc0[3] += v0.w;
        }
    }

    const float inv = 1.0f / (float)max(end - start, 1);
    float* o = out + (size_t)wave * D + lane * VEC;
    if (VEC == 2) {
        float2 v;
        v.x = (acc0[0] + acc1[0]) * inv;
        v.y = (acc0[1] + acc1[1]) * inv;
        *reinterpret_cast<float2*>(o) = v;
    } else {
        float4 v;
        v.x = (acc0[0] + acc1[0]) * inv;
        v.y = (acc0[1] + acc1[1]) * inv;
        v.z = (acc0[2] + acc1[2]) * inv;
        v.w = (acc0[3] + acc1[3]) * inv;
        *reinterpret_cast<float4*>(o) = v;
    }
}

// ---------------------------------------------------------------------------
// Fused SAGE GEMM v2: C[m][n] = act( A1[m].B1[:,n] + A2[m].B2[:,n] + bias[n] )
// Full-N blocks: BN == N, grid = M/BM row blocks -> A fetched exactly ONCE
// from HBM (B is tiny and L2-resident; old version re-read A N/64 times).
// As stored transposed [k][m] so the inner loop is pure float4 LDS reads:
// per thread-k: 1 (or 1 float2) A read + G float4 B reads feeding ROWS*G*4
// FMAs. For BM=64,BN=256: 64 FMA per 5 ds_read_b128 -> VALU-bound
// (128 VALU cyc vs ~60 LDS cyc per wave-k).
// Inner-loop LDS reads are conflict-free: B addresses are 16 contiguous
// 16B words (tx), broadcast across ty; A is 4 distinct 16B words, broadcast
// across tx. Staging-write conflicts (4-8 way) cost <5% of the tile's VALU.
// ---------------------------------------------------------------------------
template <int BM, int BN>
__global__ __launch_bounds__(256) void gemm_sage(
    const float* __restrict__ A1, const float* __restrict__ A2,
    const float* __restrict__ B1, const float* __restrict__ B2,
    const float* __restrict__ bias, float* __restrict__ C,
    int K1, int K2, int do_relu)
{
    constexpr int BK = 32;
    constexpr int ROWS = BM / 16;        // rows per thread (4 or 2)
    constexpr int G = BN / 64;           // float4 col groups per thread (4 or 1)
    constexpr int AF4 = (BM * 8) / 256;  // float4 A loads per thread (2 or 1)
    constexpr int BF4 = (BN * 8) / 256;  // float4 B loads per thread (8 or 2)

    __shared__ float As[BK][BM + 4];     // [k][m], row stride mult of 16B
    __shared__ float Bs[BK][BN + 4];     // [k][n]

    const int tid = threadIdx.x;
    const int m0 = blockIdx.x * BM;
    const int ty = tid >> 4;             // 0..15
    const int tx = tid & 15;             // 0..15

    float acc[ROWS][G * 4];
#pragma unroll
    for (int i = 0; i < ROWS; i++)
#pragma unroll
        for (int j = 0; j < G * 4; j++) acc[i][j] = 0.0f;

    const int K = K1 + K2;
    for (int kt = 0; kt < K; kt += BK) {
        const float* Ap; const float* Bp; int lK, kof;
        if (kt < K1) { Ap = A1; Bp = B1; lK = K1; kof = kt; }
        else         { Ap = A2; Bp = B2; lK = K2; kof = kt - K1; }

        // stage A tile (BM x 32) transposed into As[k][m]
#pragma unroll
        for (int j = 0; j < AF4; j++) {
            int id = tid * AF4 + j;
            int m = id >> 3;             // 8 float4 per row of 32 k
            int q = id & 7;
            float4 v = *reinterpret_cast<const float4*>(
                Ap + (size_t)(m0 + m) * lK + kof + q * 4);
            As[q * 4 + 0][m] = v.x;
            As[q * 4 + 1][m] = v.y;
            As[q * 4 + 2][m] = v.z;
            As[q * 4 + 3][m] = v.w;
        }
        // stage B tile (32 x BN)
#pragma unroll
        for (int j = 0; j < BF4; j++) {
            int id = tid * BF4 + j;
            int k = id / (BN / 4);
            int c = id % (BN / 4);
            float4 v = *reinterpret_cast<const float4*>(
                Bp + (size_t)(kof + k) * BN + c * 4);
            *reinterpret_cast<float4*>(&Bs[k][c * 4]) = v;
        }
        __syncthreads();

#pragma unroll
        for (int kk = 0; kk < BK; kk++) {
            float a[ROWS];
            if constexpr (ROWS == 4) {
                float4 av = *reinterpret_cast<const float4*>(&As[kk][ty * 4]);
                a[0] = av.x; a[1] = av.y; a[2] = av.z; a[3] = av.w;
            } else {
                float2 av = *reinterpret_cast<const float2*>(&As[kk][ty * 2]);
                a[0] = av.x; a[1] = av.y;
            }
#pragma unroll
            for (int g = 0; g < G; g++) {
                float4 bv = *reinterpret_cast<const float4*>(&Bs[kk][g * 64 + tx * 4]);
                const float b[4] = {bv.x, bv.y, bv.z, bv.w};
#pragma unroll
                for (int i = 0; i < ROWS; i++)
#pragma unroll
                    for (int jj = 0; jj < 4; jj++)
                        acc[i][g * 4 + jj] += a[i] * b[jj];
            }
        }
        __syncthreads();
    }

    // epilogue: bias + optional relu, float4 stores (C row stride == BN == N)
#pragma unroll
    for (int i = 0; i < ROWS; i++) {
        const int row = m0 + ty * ROWS + i;
#pragma unroll
        for (int g = 0; g < G; g++) {
            const float4 bb = *reinterpret_cast<const float4*>(bias + g * 64 + tx * 4);
            float v0 = acc[i][g * 4 + 0] + bb.x;
            float v1 = acc[i][g * 4 + 1] + bb.y;
            float v2 = acc[i][g * 4 + 2] + bb.z;
            float v3 = acc[i][g * 4 + 3] + bb.w;
            if (do_relu) {
                v0 = fmaxf(v0, 0.0f); v1 = fmaxf(v1, 0.0f);
                v2 = fmaxf(v2, 0.0f); v3 = fmaxf(v3, 0.0f);
            }
            float4 o; o.x = v0; o.y = v1; o.z = v2; o.w = v3;
            *reinterpret_cast<float4*>(C + (size_t)row * BN + g * 64 + tx * 4) = o;
        }
    }
}

extern "C" void kernel_launch(void* const* d_in, const int* in_sizes, int n_in,
                              void* d_out, int out_size, void* d_ws, size_t ws_size,
                              hipStream_t stream)
{
    const float* x   = (const float*)d_in[0];
    const float* Wl0 = (const float*)d_in[1];
    const float* bl0 = (const float*)d_in[2];
    const float* Wr0 = (const float*)d_in[3];
    const float* Wl1 = (const float*)d_in[4];
    const float* bl1 = (const float*)d_in[5];
    const float* Wr1 = (const float*)d_in[6];
    const float* Wl2 = (const float*)d_in[7];
    const float* bl2 = (const float*)d_in[8];
    const float* Wr2 = (const float*)d_in[9];
    const int* es0 = (const int*)d_in[10];
    const int* ed0 = (const int*)d_in[11];
    const int* es1 = (const int*)d_in[12];
    const int* ed1 = (const int*)d_in[13];
    const int* es2 = (const int*)d_in[14];
    const int* ed2 = (const int*)d_in[15];

    // Workspace layout (4B units). Only bk* needs zeroing.
    int* bk0   = (int*)d_ws;                       // SZ1
    int* bk1   = bk0 + SZ1;                        // SZ2
    int* bk2   = bk1 + SZ2;                        // SZ3
    int* perm0 = bk2 + SZ3;                        // NE0
    int* perm1 = perm0 + NE0;                      // NE1
    int* perm2 = perm1 + NE1;                      // NE2
    float* agg0 = (float*)(perm2 + NE2);           // SZ1*DIN
    float* agg1 = agg0 + (size_t)SZ1 * DIN;        // SZ2*DH
    float* agg2 = agg1 + (size_t)SZ2 * DH;         // SZ3*DH
    float* h1   = agg2 + (size_t)SZ3 * DH;         // SZ1*DH
    float* h2   = agg0;  // alias: agg0 is dead after gemm0; SZ2*DH <= SZ1*DIN
    // total distinct: ~208.9 MB

    hipMemsetAsync(bk0, 0, (size_t)(SZ1 + SZ2 + SZ3) * sizeof(int), stream);

    // ---- layer 0: x(1363968x128) -> h1(123904x256), relu ----
    edge_hist<<<(NE0 + 255) / 256, 256, 0, stream>>>(ed0, bk0, NE0);
    scan_inplace<<<1, 1024, 0, stream>>>(bk0, SZ1);
    edge_bucket<<<(NE0 + 255) / 256, 256, 0, stream>>>(es0, ed0, bk0, perm0, NE0);
    gather_mean<DIN><<<SZ1 / 4, 256, 0, stream>>>(x, perm0, bk0, agg0);
    gemm_sage<64, DH><<<SZ1 / 64, 256, 0, stream>>>(
        agg0, x, Wl0, Wr0, bl0, h1, DIN, DIN, 1);

    // ---- layer 1: h1 -> h2(11264x256), no relu ----
    edge_hist<<<(NE1 + 255) / 256, 256, 0, stream>>>(ed1, bk1, NE1);
    scan_inplace<<<1, 1024, 0, stream>>>(bk1, SZ2);
    edge_bucket<<<(NE1 + 255) / 256, 256, 0, stream>>>(es1, ed1, bk1, perm1, NE1);
    gather_mean<DH><<<SZ2 / 4, 256, 0, stream>>>(h1, perm1, bk1, agg1);
    gemm_sage<32, DH><<<SZ2 / 32, 256, 0, stream>>>(
        agg1, h1, Wl1, Wr1, bl1, h2, DH, DH, 0);

    // ---- layer 2: h2 -> out(1024x64), relu ----
    edge_hist<<<(NE2 + 255) / 256, 256, 0, stream>>>(ed2, bk2, NE2);
    scan_inplace<<<1, 1024, 0, stream>>>(bk2, SZ3);
    edge_bucket<<<(NE2 + 255) / 256, 256, 0, stream>>>(es2, ed2, bk2, perm2, NE2);
    gather_mean<DH><<<SZ3 / 4, 256, 0, stream>>>(h2, perm2, bk2, agg2);
    gemm_sage<32, DOUT><<<SZ3 / 32, 256, 0, stream>>>(
        agg2, h2, Wl2, Wr2, bl2, (float*)d_out, DH, DH, 1);
}